// Round 2
// baseline (527.662 us; speedup 1.0000x reference)
//
#include <hip/hip_runtime.h>
#include <math.h>

#define B_ 16
#define W_ 512
#define H_ 512
#define S_ (W_*H_)
#define ALPHA_ 0.15f
#define MU_ 10.0f
#define TAU_ 0.125f
#define SIG_ 0.125f
#define EPS_ 1e-6f
#define INV1PT_ (1.0f/(1.0f+TAU_))
#define NBINS 4096
#define BINSCALE 2048.0f
#define BINW (1.0f/2048.0f)

// ---- K1: horizontal 31-tap max via log-tree sliding max ----
__global__ __launch_bounds__(256) void hmax_kernel(const float* __restrict__ Iy,
                                                   float* __restrict__ Rh,
                                                   float* __restrict__ GBh){
  __shared__ float bufA[2][544], bufB[2][544];
  int t = threadIdx.x;
  int b = blockIdx.x >> 9;
  int i = blockIdx.x & 511;
  const float* row = Iy + (size_t)b*3*S_ + (size_t)i*W_;
  for (int p = t; p < 544; p += 256){
    int idx = p - 16;
    bool v = (idx >= 0) && (idx < 512);
    bufA[0][p] = v ? row[idx] : -1e30f;
    bufA[1][p] = v ? fmaxf(row[S_+idx], row[2*S_+idx]) : -1e30f;
  }
  __syncthreads();
  float (*src)[544] = bufA; float (*dst)[544] = bufB;
  const int ds[5] = {1, 2, 4, 8, 15};
  #pragma unroll
  for (int sstep = 0; sstep < 5; ++sstep){
    int d = ds[sstep];
    for (int p = t; p < 544; p += 256){
      int q = min(p + d, 543);
      dst[0][p] = fmaxf(src[0][p], src[0][q]);
      dst[1][p] = fmaxf(src[1][p], src[1][q]);
    }
    __syncthreads();
    float (*tmp)[544] = src; src = dst; dst = tmp;
  }
  size_t o = (size_t)b*S_ + (size_t)i*W_;
  for (int p = t; p < 512; p += 256){
    Rh[o+p]  = src[0][p+1];
    GBh[o+p] = src[1][p+1];
  }
}

// ---- vertical van Herk forward scan (31-row aligned chunks) ----
__global__ __launch_bounds__(256) void vscan_fwd_kernel(const float* __restrict__ Rh,
                                                        const float* __restrict__ GBh,
                                                        float* __restrict__ Rf,
                                                        float* __restrict__ Gf){
  int gid = blockIdx.x*256 + threadIdx.x;     // 544 blocks = 8192 cols * 17 chunks
  int col = gid & 8191;
  int c   = gid >> 13;                        // 0..16
  int b = col >> 9, j = col & 511;
  int i0 = c*31, i1 = min(i0+31, H_);
  size_t base = (size_t)b*S_ + j;
  float rR = -1e30f, rG = -1e30f;
  for (int i = i0; i < i1; ++i){
    size_t o = base + (size_t)i*W_;
    rR = fmaxf(rR, Rh[o]); rG = fmaxf(rG, GBh[o]);
    Rf[o] = rR; Gf[o] = rG;
  }
}

// ---- vertical bwd scan; x = |Rmax - GBmax| + R ----
__global__ __launch_bounds__(256) void vscan_bwd_kernel(const float* __restrict__ Rh,
                                                        const float* __restrict__ GBh,
                                                        const float* __restrict__ Rf,
                                                        const float* __restrict__ Gf,
                                                        const float* __restrict__ Iy,
                                                        float* __restrict__ xo){
  int gid = blockIdx.x*256 + threadIdx.x;
  int col = gid & 8191;
  int c   = gid >> 13;
  int b = col >> 9, j = col & 511;
  int i0 = c*31, i1 = min(i0+31, H_);
  size_t base = (size_t)b*S_ + j;
  const float* IyR = Iy + (size_t)b*3*S_ + j;
  float lR = -1e30f, lG = -1e30f;
  for (int i = i1-1; i >= i0; --i){
    size_t o64 = base + (size_t)i*W_;
    lR = fmaxf(lR, Rh[o64]); lG = fmaxf(lG, GBh[o64]);
    int o = i + 15;
    if (o < H_){
      int bi = min(i + 30, H_-1);
      size_t ob = base + (size_t)bi*W_;
      float mR = fmaxf(lR, Rf[ob]);
      float mG = fmaxf(lG, Gf[ob]);
      xo[base + (size_t)o*W_] = fabsf(mR - mG) + IyR[(size_t)o*W_];
    }
  }
  if (c == 0){
    for (int o = 0; o < 15; ++o){
      size_t ob = base + (size_t)(o+15)*W_;
      float mR = Rf[ob], mG = Gf[ob];
      xo[base + (size_t)o*W_] = fabsf(mR - mG) + IyR[(size_t)o*W_];
    }
  }
}

// ---- per-block PARTIAL histograms of x ----
__global__ __launch_bounds__(256) void hist_build_kernel(const float* __restrict__ data,
                                                         unsigned int* __restrict__ hist){
  __shared__ unsigned int h[NBINS];
  int t = threadIdx.x;
  int b = blockIdx.x >> 4, sub = blockIdx.x & 15;
  for (int p = t; p < NBINS; p += 256) h[p] = 0u;
  __syncthreads();
  const float* p = data + (size_t)b*S_ + (size_t)sub*16384;
  for (int k = 0; k < 64; ++k){
    float x = p[k*256 + t];
    int bin = (int)(x*BINSCALE);
    bin = min(max(bin, 0), NBINS-1);
    atomicAdd(&h[bin], 1u);
  }
  __syncthreads();
  unsigned int* hb = hist + (size_t)(b*16 + sub)*NBINS;
  for (int q = t; q < NBINS; q += 256) hb[q] = h[q];
}

// ---- partial histograms of grad-mag computed on-the-fly from nh ----
__global__ __launch_bounds__(256) void hist_gm_kernel(const float* __restrict__ nh,
                                                      unsigned int* __restrict__ hist){
  __shared__ unsigned int h[NBINS];
  int t = threadIdx.x;
  int b = blockIdx.x >> 4, sub = blockIdx.x & 15;
  for (int p = t; p < NBINS; p += 256) h[p] = 0u;
  __syncthreads();
  const float* base = nh + (size_t)b*S_;
  int i0 = sub*16384;
  for (int k = 0; k < 64; ++k){
    int idx = i0 + k*256 + t;
    int row = idx >> 9, col = idx & 511;
    float c = base[idx];
    float dx = (col < W_-1) ? base[idx+1]   - c : 0.f;
    float dy = (row < H_-1) ? base[idx+W_]  - c : 0.f;
    float g = sqrtf(dx*dx + dy*dy + EPS_);
    int bin = (int)(g*BINSCALE);
    bin = min(max(bin, 0), NBINS-1);
    atomicAdd(&h[bin], 1u);
  }
  __syncthreads();
  unsigned int* hb = hist + (size_t)(b*16 + sub)*NBINS;
  for (int q = t; q < NBINS; q += 256) hb[q] = h[q];
}

// ---- pick order statistics ----
__global__ __launch_bounds__(256) void pick_hist_kernel(
    const unsigned int* __restrict__ hist, int r0, int r1, int r2, int r3,
    int nranks, float* __restrict__ outv, int which){
  __shared__ unsigned int part[256];
  __shared__ int s_own[4], s_rem[4];
  __shared__ float s_val[4];
  int t = threadIdx.x, b = blockIdx.x;
  const unsigned int* hb = hist + (size_t)b*16*NBINS;
  unsigned int binc[16];
  #pragma unroll
  for (int k = 0; k < 16; ++k) binc[k] = 0u;
  for (int sub = 0; sub < 16; ++sub){
    const unsigned int* hp = hb + (size_t)sub*NBINS + t*16;
    #pragma unroll
    for (int k = 0; k < 16; ++k) binc[k] += hp[k];
  }
  unsigned int sum = 0u;
  #pragma unroll
  for (int k = 0; k < 16; ++k) sum += binc[k];
  part[t] = sum;
  __syncthreads();
  if (t == 0){
    int rk[4] = {r0, r1, r2, r3};
    for (int ri = 0; ri < nranks; ++ri){
      int rem = rk[ri]; int own = 255;
      for (int q = 0; q < 256; ++q){
        if ((unsigned int)rem < part[q]){ own = q; break; }
        rem -= (int)part[q];
      }
      s_own[ri] = own; s_rem[ri] = rem;
    }
  }
  __syncthreads();
  for (int ri = 0; ri < nranks; ++ri){
    if (t == s_own[ri]){
      int rem = s_rem[ri]; int bin = t*16 + 15;
      #pragma unroll
      for (int q = 0; q < 16; ++q){
        if ((unsigned int)rem < binc[q]){ bin = t*16 + q; break; }
        rem -= (int)binc[q];
      }
      s_val[ri] = ((float)bin + 0.5f) * BINW;
    }
  }
  __syncthreads();
  if (t == 0){
    if (which == 0){
      outv[2*b+0] = s_val[0]*0.57f + s_val[1]*0.43f;   // lo (pos frac .43)
      outv[2*b+1] = s_val[2]*0.43f + s_val[3]*0.57f;   // hi (pos frac .57)
    } else {
      outv[b] = fmaxf(0.5f*(s_val[0] + s_val[1]), EPS_); // median -> sigma
    }
  }
}

// ---- N_hat only, vectorized ----
__global__ __launch_bounds__(256) void nhat_kernel(const float* __restrict__ x,
                                                   const float* __restrict__ vx2,
                                                   float* __restrict__ nh){
  size_t i4 = (size_t)blockIdx.x*256 + threadIdx.x;   // float4 index
  int b = (int)(i4 >> 16);
  float lo = vx2[2*b], hi = vx2[2*b+1];
  float inv = 1.0f/(hi - lo + EPS_);
  float4 v = ((const float4*)x)[i4];
  v.x = fminf(fmaxf((v.x-lo)*inv, 0.f), 1.f);
  v.y = fminf(fmaxf((v.y-lo)*inv, 0.f), 1.f);
  v.z = fminf(fmaxf((v.z-lo)*inv, 0.f), 1.f);
  v.w = fminf(fmaxf((v.w-lo)*inv, 0.f), 1.f);
  ((float4*)nh)[i4] = v;
}

// ---- fused T-iteration primal-dual: TILE 64 / CORE 48 / 512 thr / 8 px ----
#define TILE 64
#define CORE 48
#define HALO 8
#define NB 11   // ceil(512/48)
#define PSTR 68 // padded row stride (variant C): 68 mod 32 = 4 -> clean stripes

template<int PADDED>
__device__ __forceinline__ int ADDR(int row, int col){
  return PADDED ? (row*PSTR + col)
                : ((row<<6) | ((((col>>2) ^ (row & 15)) << 2) | (col & 3)));
}
template<int PADDED>
__device__ __forceinline__ int ADDR4(int row, int g){
  return PADDED ? (row*PSTR + (g<<2))
                : ((row<<6) | ((g ^ (row & 15)) << 2));
}

#define AW_(d) (ALPHA_*(1.0f + MU_*__expf(-fabsf(d)*invs)))

// Variants: A = <4,0> (prev-round baseline: VGPR cap 64, XOR swizzle)
//           B = <2,0> (VGPR cap 256 -> no spills, XOR swizzle)
//           C = <2,1> (VGPR cap 256, padded stride-68 LDS)
template<int MINW, int PADDED>
__global__ __launch_bounds__(512, MINW) void pd_fused_kernel(
    const float* __restrict__ u_in,  const float* __restrict__ ub_in,
    const float* __restrict__ px_in, const float* __restrict__ py_in,
    float* __restrict__ u_out,  float* __restrict__ ub_out,
    float* __restrict__ px_out, float* __restrict__ py_out,
    const float* __restrict__ nh_g, const float* __restrict__ sig_arr,
    int T, int mode)   // mode 1 = init from nh; 2 = last launch (store clamped u)
{
  constexpr int LSZ = PADDED ? (TILE*PSTR) : (TILE*TILE);
  __shared__ float sA[LSZ], sB[LSZ];
  const int t = threadIdx.x;
  const int b = blockIdx.z;
  const int gi0 = blockIdx.y*CORE - HALO;
  const int gj0 = blockIdx.x*CORE - HALO;
  const float invs = 1.0f / sig_arr[b];
  const int pi = t >> 4, pj = t & 15;      // 32 x 16 thread grid
  const int r0 = 2*pi, c0 = 4*pj;          // 2-tall x 4-wide pixels per thread
  const size_t bb = (size_t)b*S_;

  #define STAGE(dst, srcP, ZOOB)                                   \
    _Pragma("unroll")                                              \
    for (int k = 0; k < 8; ++k){                                   \
      int p = t + k*512; int li = p>>6, lj = p & 63;               \
      int gi = gi0+li, gj = gj0+lj;                                \
      int gic = min(max(gi,0),H_-1), gjc = min(max(gj,0),W_-1);    \
      float v = srcP[bb + (size_t)gic*W_ + gjc];                   \
      if (ZOOB && ((gi != gic) || (gj != gjc))) v = 0.f;           \
      dst[ADDR<PADDED>(li,lj)] = v; }

  // Phase A: nh into sB (and sA=ub init if mode 1)
  STAGE(sB, nh_g, 0)
  if (mode == 1){ STAGE(sA, nh_g, 0) }
  __syncthreads();

  // loop-invariant LDS addresses
  const int rU = max(r0-1,0), rD = min(r0+2,TILE-1);
  const int cl = max(c0-1,0), cr = min(c0+4,TILE-1);
  const int a_o0 = ADDR4<PADDED>(r0,  pj), a_o1 = ADDR4<PADDED>(r0+1,pj);
  const int a_up = ADDR4<PADDED>(rU,  pj), a_dn = ADDR4<PADDED>(rD,  pj);
  const int a_l0 = ADDR<PADDED>(r0,  cl), a_l1 = ADDR<PADDED>(r0+1,cl);
  const int a_r0 = ADDR<PADDED>(r0,  cr), a_r1 = ADDR<PADDED>(r0+1,cr);

  float nh_r[2][4], ax[2][4], ay[2][4], axL[2], ayU[4];
  {
    float4 n0 = *(const float4*)&sB[a_o0];
    float4 n1 = *(const float4*)&sB[a_o1];
    float4 nU = *(const float4*)&sB[a_up];
    float4 nD = *(const float4*)&sB[a_dn];
    float nR0 = sB[a_r0], nR1 = sB[a_r1];
    float nL0 = sB[a_l0], nL1 = sB[a_l1];
    float n0a[4] = {n0.x,n0.y,n0.z,n0.w};
    float n1a[4] = {n1.x,n1.y,n1.z,n1.w};
    float nUa[4] = {nU.x,nU.y,nU.z,nU.w};
    float nDa[4] = {nD.x,nD.y,nD.z,nD.w};
    const int gir = gi0 + r0;
    const int giU = gir - 1;
    #pragma unroll
    for (int c = 0; c < 4; ++c){
      nh_r[0][c] = n0a[c]; nh_r[1][c] = n1a[c];
      int gj = gj0 + c0 + c;
      float nhR0 = (c<3) ? n0a[c+1] : nR0;
      float nhR1 = (c<3) ? n1a[c+1] : nR1;
      bool jb = (gj < 0) || (gj >= W_-1);
      ax[0][c] = jb ? 0.f : AW_(nhR0 - n0a[c]);
      ax[1][c] = jb ? 0.f : AW_(nhR1 - n1a[c]);
      ay[0][c] = (gir   < 0 || gir   >= H_-1) ? 0.f : AW_(n1a[c] - n0a[c]);
      ay[1][c] = (gir+1 < 0 || gir+1 >= H_-1) ? 0.f : AW_(nDa[c] - n1a[c]);
      float nhDU = (r0 > 0) ? n0a[c] : n1a[c];
      ayU[c] = (giU < 0 || giU >= H_-1) ? 0.f : AW_(nhDU - nUa[c]);
    }
    int gjL = gj0 + c0 - 1;
    float nhRL0 = (c0 > 0) ? n0a[0] : n0a[1];
    float nhRL1 = (c0 > 0) ? n1a[0] : n1a[1];
    bool lb = (gjL < 0) || (gjL >= W_-1);
    axL[0] = lb ? 0.f : AW_(nhRL0 - nL0);
    axL[1] = lb ? 0.f : AW_(nhRL1 - nL1);
  }

  float u_r[2][4], px_r[2][4], py_r[2][4], pxL[2], pyU[4], ubw[2][4];
  if (mode == 1){
    #pragma unroll
    for (int r = 0; r < 2; ++r)
    #pragma unroll
    for (int c = 0; c < 4; ++c){ u_r[r][c] = nh_r[r][c]; px_r[r][c] = 0.f; py_r[r][c] = 0.f; }
    pxL[0]=pxL[1]=0.f; pyU[0]=pyU[1]=pyU[2]=pyU[3]=0.f;
  } else {
    __syncthreads();
    STAGE(sB, u_in, 0)
    __syncthreads();
    { float4 v0 = *(const float4*)&sB[a_o0];
      float4 v1 = *(const float4*)&sB[a_o1];
      u_r[0][0]=v0.x; u_r[0][1]=v0.y; u_r[0][2]=v0.z; u_r[0][3]=v0.w;
      u_r[1][0]=v1.x; u_r[1][1]=v1.y; u_r[1][2]=v1.z; u_r[1][3]=v1.w; }
    __syncthreads();
    STAGE(sB, px_in, 1)
    __syncthreads();
    { float4 v0 = *(const float4*)&sB[a_o0];
      float4 v1 = *(const float4*)&sB[a_o1];
      px_r[0][0]=v0.x; px_r[0][1]=v0.y; px_r[0][2]=v0.z; px_r[0][3]=v0.w;
      px_r[1][0]=v1.x; px_r[1][1]=v1.y; px_r[1][2]=v1.z; px_r[1][3]=v1.w;
      pxL[0] = sB[a_l0]; pxL[1] = sB[a_l1]; }
    __syncthreads();
    STAGE(sB, py_in, 1)
    __syncthreads();
    { float4 v0 = *(const float4*)&sB[a_o0];
      float4 v1 = *(const float4*)&sB[a_o1];
      float4 vu = *(const float4*)&sB[a_up];
      py_r[0][0]=v0.x; py_r[0][1]=v0.y; py_r[0][2]=v0.z; py_r[0][3]=v0.w;
      py_r[1][0]=v1.x; py_r[1][1]=v1.y; py_r[1][2]=v1.z; py_r[1][3]=v1.w;
      pyU[0]=vu.x; pyU[1]=vu.y; pyU[2]=vu.z; pyU[3]=vu.w; }
    __syncthreads();
    STAGE(sA, ub_in, 0)
  }
  __syncthreads();

  for (int s = 0; s < T; ++s){
    float* RB = (s & 1) ? sB : sA;
    float* WB = (s & 1) ? sA : sB;
    float4 o0 = *(const float4*)&RB[a_o0];
    float4 o1 = *(const float4*)&RB[a_o1];
    float4 up = *(const float4*)&RB[a_up];
    float4 dn = *(const float4*)&RB[a_dn];
    float Lv0 = RB[a_l0], Lv1 = RB[a_l1];
    float Rv0 = RB[a_r0], Rv1 = RB[a_r1];
    float ub0[4] = {o0.x,o0.y,o0.z,o0.w};
    float ub1[4] = {o1.x,o1.y,o1.z,o1.w};
    float upa[4] = {up.x,up.y,up.z,up.w};
    float dna[4] = {dn.x,dn.y,dn.z,dn.w};

    pxL[0] = fminf(fmaxf(fmaf(SIG_, ub0[0]-Lv0, pxL[0]), -axL[0]), axL[0]);
    pxL[1] = fminf(fmaxf(fmaf(SIG_, ub1[0]-Lv1, pxL[1]), -axL[1]), axL[1]);
    #pragma unroll
    for (int c = 0; c < 4; ++c)
      pyU[c] = fminf(fmaxf(fmaf(SIG_, ub0[c]-upa[c], pyU[c]), -ayU[c]), ayU[c]);
    #pragma unroll
    for (int c = 0; c < 4; ++c){
      float ubR0 = (c<3) ? ub0[c+1] : Rv0;
      float ubR1 = (c<3) ? ub1[c+1] : Rv1;
      px_r[0][c] = fminf(fmaxf(fmaf(SIG_, ubR0-ub0[c], px_r[0][c]), -ax[0][c]), ax[0][c]);
      px_r[1][c] = fminf(fmaxf(fmaf(SIG_, ubR1-ub1[c], px_r[1][c]), -ax[1][c]), ax[1][c]);
      py_r[0][c] = fminf(fmaxf(fmaf(SIG_, ub1[c]-ub0[c], py_r[0][c]), -ay[0][c]), ay[0][c]);
      py_r[1][c] = fminf(fmaxf(fmaf(SIG_, dna[c]-ub1[c], py_r[1][c]), -ay[1][c]), ay[1][c]);
    }
    #pragma unroll
    for (int c = 0; c < 4; ++c){
      float pxl0 = (c>0) ? px_r[0][c-1] : pxL[0];
      float pxl1 = (c>0) ? px_r[1][c-1] : pxL[1];
      float div0 = px_r[0][c] + py_r[0][c] - pxl0 - pyU[c];
      float div1 = px_r[1][c] + py_r[1][c] - pxl1 - py_r[0][c];
      float un0 = fmaf(TAU_, div0 + nh_r[0][c], u_r[0][c]) * INV1PT_;
      float un1 = fmaf(TAU_, div1 + nh_r[1][c], u_r[1][c]) * INV1PT_;
      ubw[0][c] = 2.f*un0 - u_r[0][c];
      ubw[1][c] = 2.f*un1 - u_r[1][c];
      u_r[0][c] = un0; u_r[1][c] = un1;
    }
    *(float4*)&WB[a_o0] = make_float4(ubw[0][0],ubw[0][1],ubw[0][2],ubw[0][3]);
    *(float4*)&WB[a_o1] = make_float4(ubw[1][0],ubw[1][1],ubw[1][2],ubw[1][3]);
    __syncthreads();
  }

  // epilogue: core is cols 8..55 (pj 2..13, full float4), rows 8..55
  #pragma unroll
  for (int r = 0; r < 2; ++r){
    int li = r0 + r;
    int gi = gi0 + li;
    if (li >= HALO && li < HALO+CORE && pj >= 2 && pj <= 13 && gi < H_){
      int gj = gj0 + c0;
      if (gj < W_){
        size_t g = bb + (size_t)gi*W_ + gj;
        if (mode == 2){
          *(float4*)&u_out[g] = make_float4(
            fminf(fmaxf(u_r[r][0],0.f),1.f), fminf(fmaxf(u_r[r][1],0.f),1.f),
            fminf(fmaxf(u_r[r][2],0.f),1.f), fminf(fmaxf(u_r[r][3],0.f),1.f));
        } else {
          *(float4*)&u_out[g]  = make_float4(u_r[r][0], u_r[r][1], u_r[r][2], u_r[r][3]);
          *(float4*)&ub_out[g] = make_float4(ubw[r][0], ubw[r][1], ubw[r][2], ubw[r][3]);
          *(float4*)&px_out[g] = make_float4(px_r[r][0],px_r[r][1],px_r[r][2],px_r[r][3]);
          *(float4*)&py_out[g] = make_float4(py_r[r][0],py_r[r][1],py_r[r][2],py_r[r][3]);
        }
      }
    }
  }
}

extern "C" void kernel_launch(void* const* d_in, const int* in_sizes, int n_in,
                              void* d_out, int out_size, void* d_ws, size_t ws_size,
                              hipStream_t stream){
  const float* Iy = (const float*)d_in[0];
  float* out = (float*)d_out;
  char* ws = (char*)d_ws;
  const size_t SLOT = (size_t)B_*S_*sizeof(float);
  float* slot[8];
  for (int q = 0; q < 8; ++q) slot[q] = (float*)(ws + (size_t)q*SLOT);
  float* vx2 = (float*)(ws + (size_t)8*SLOT);  // lo,hi per batch (32 floats)
  float* sig = vx2 + 32;                       // sigma per batch (16 floats)

  float* Rh  = slot[0];
  float* GBh = slot[1];
  float* Rf  = slot[5];
  float* Gf  = slot[6];
  float* xb  = slot[2];
  float* nh  = slot[3];
  unsigned int* hist_x  = (unsigned int*)(ws + (size_t)4*SLOT);   // 4 MiB
  unsigned int* hist_gm = hist_x + (size_t)256*NBINS;             // 4 MiB

  hmax_kernel<<<B_*H_, 256, 0, stream>>>(Iy, Rh, GBh);
  vscan_fwd_kernel<<<544, 256, 0, stream>>>(Rh, GBh, Rf, Gf);
  vscan_bwd_kernel<<<544, 256, 0, stream>>>(Rh, GBh, Rf, Gf, Iy, xb);
  hist_build_kernel<<<256, 256, 0, stream>>>(xb, hist_x);
  // ranks: floor/ceil of 0.01*(N-1)=2621.43 and 0.99*(N-1)=259521.57
  pick_hist_kernel<<<B_, 256, 0, stream>>>(hist_x, 2621, 2622, 259521, 259522, 4, vx2, 0);
  nhat_kernel<<<B_*S_/4/256, 256, 0, stream>>>(xb, vx2, nh);
  hist_gm_kernel<<<256, 256, 0, stream>>>(nh, hist_gm);
  // median ranks 131071, 131072
  pick_hist_kernel<<<B_, 256, 0, stream>>>(hist_gm, 131071, 131072, 0, 0, 2, sig, 1);

  float *uA = slot[1], *ubA = slot[2], *pxA = slot[5], *pyA = slot[6];
  float *uB = slot[0], *ubB = slot[4], *pxB = slot[7], *pyB = out;

  dim3 pdg(NB, NB, B_);
  // L1: variant C (mode 1)
  pd_fused_kernel<2,1><<<pdg, 512, 0, stream>>>(nh, nh, nh, nh,
                                                uA, ubA, pxA, pyA, nh, sig, 8, 1);
  // L2: variant A (prev-round baseline, mode 0) -- in-run control
  pd_fused_kernel<4,0><<<pdg, 512, 0, stream>>>(uA, ubA, pxA, pyA,
                                                uB, ubB, pxB, pyB, nh, sig, 8, 0);
  // L3: variant B (no VGPR cap, mode 0) -- isolates the spill theory
  pd_fused_kernel<2,0><<<pdg, 512, 0, stream>>>(uB, ubB, pxB, pyB,
                                                uA, ubA, pxA, pyA, nh, sig, 8, 0);
  // L4: variant C (mode 2): clamp u straight into out
  pd_fused_kernel<2,1><<<pdg, 512, 0, stream>>>(uA, ubA, pxA, pyA,
                                                out, slot[7], slot[7], slot[7], nh, sig, 6, 2);
}

// Round 3
// 475.059 us; speedup vs baseline: 1.1107x; 1.1107x over previous
//
#include <hip/hip_runtime.h>
#include <math.h>

#define B_ 16
#define W_ 512
#define H_ 512
#define S_ (W_*H_)
#define ALPHA_ 0.15f
#define MU_ 10.0f
#define TAU_ 0.125f
#define SIG_ 0.125f
#define EPS_ 1e-6f
#define INV1PT_ (1.0f/(1.0f+TAU_))
#define NBINS 4096
#define BINSCALE 2048.0f
#define BINW (1.0f/2048.0f)

// ---- K1: horizontal 31-tap max via log-tree sliding max ----
__global__ __launch_bounds__(256) void hmax_kernel(const float* __restrict__ Iy,
                                                   float* __restrict__ Rh,
                                                   float* __restrict__ GBh){
  __shared__ float bufA[2][544], bufB[2][544];
  int t = threadIdx.x;
  int b = blockIdx.x >> 9;
  int i = blockIdx.x & 511;
  const float* row = Iy + (size_t)b*3*S_ + (size_t)i*W_;
  for (int p = t; p < 544; p += 256){
    int idx = p - 16;
    bool v = (idx >= 0) && (idx < 512);
    bufA[0][p] = v ? row[idx] : -1e30f;
    bufA[1][p] = v ? fmaxf(row[S_+idx], row[2*S_+idx]) : -1e30f;
  }
  __syncthreads();
  float (*src)[544] = bufA; float (*dst)[544] = bufB;
  const int ds[5] = {1, 2, 4, 8, 15};
  #pragma unroll
  for (int sstep = 0; sstep < 5; ++sstep){
    int d = ds[sstep];
    for (int p = t; p < 544; p += 256){
      int q = min(p + d, 543);
      dst[0][p] = fmaxf(src[0][p], src[0][q]);
      dst[1][p] = fmaxf(src[1][p], src[1][q]);
    }
    __syncthreads();
    float (*tmp)[544] = src; src = dst; dst = tmp;
  }
  size_t o = (size_t)b*S_ + (size_t)i*W_;
  for (int p = t; p < 512; p += 256){
    Rh[o+p]  = src[0][p+1];
    GBh[o+p] = src[1][p+1];
  }
}

// ---- vertical van Herk forward scan (31-row aligned chunks) ----
__global__ __launch_bounds__(256) void vscan_fwd_kernel(const float* __restrict__ Rh,
                                                        const float* __restrict__ GBh,
                                                        float* __restrict__ Rf,
                                                        float* __restrict__ Gf){
  int gid = blockIdx.x*256 + threadIdx.x;     // 544 blocks = 8192 cols * 17 chunks
  int col = gid & 8191;
  int c   = gid >> 13;                        // 0..16
  int b = col >> 9, j = col & 511;
  int i0 = c*31, i1 = min(i0+31, H_);
  size_t base = (size_t)b*S_ + j;
  float rR = -1e30f, rG = -1e30f;
  for (int i = i0; i < i1; ++i){
    size_t o = base + (size_t)i*W_;
    rR = fmaxf(rR, Rh[o]); rG = fmaxf(rG, GBh[o]);
    Rf[o] = rR; Gf[o] = rG;
  }
}

// ---- vertical bwd scan; x = |Rmax - GBmax| + R ----
__global__ __launch_bounds__(256) void vscan_bwd_kernel(const float* __restrict__ Rh,
                                                        const float* __restrict__ GBh,
                                                        const float* __restrict__ Rf,
                                                        const float* __restrict__ Gf,
                                                        const float* __restrict__ Iy,
                                                        float* __restrict__ xo){
  int gid = blockIdx.x*256 + threadIdx.x;
  int col = gid & 8191;
  int c   = gid >> 13;
  int b = col >> 9, j = col & 511;
  int i0 = c*31, i1 = min(i0+31, H_);
  size_t base = (size_t)b*S_ + j;
  const float* IyR = Iy + (size_t)b*3*S_ + j;
  float lR = -1e30f, lG = -1e30f;
  for (int i = i1-1; i >= i0; --i){
    size_t o64 = base + (size_t)i*W_;
    lR = fmaxf(lR, Rh[o64]); lG = fmaxf(lG, GBh[o64]);
    int o = i + 15;
    if (o < H_){
      int bi = min(i + 30, H_-1);
      size_t ob = base + (size_t)bi*W_;
      float mR = fmaxf(lR, Rf[ob]);
      float mG = fmaxf(lG, Gf[ob]);
      xo[base + (size_t)o*W_] = fabsf(mR - mG) + IyR[(size_t)o*W_];
    }
  }
  if (c == 0){
    for (int o = 0; o < 15; ++o){
      size_t ob = base + (size_t)(o+15)*W_;
      float mR = Rf[ob], mG = Gf[ob];
      xo[base + (size_t)o*W_] = fabsf(mR - mG) + IyR[(size_t)o*W_];
    }
  }
}

// ---- per-block PARTIAL histograms of x ----
__global__ __launch_bounds__(256) void hist_build_kernel(const float* __restrict__ data,
                                                         unsigned int* __restrict__ hist){
  __shared__ unsigned int h[NBINS];
  int t = threadIdx.x;
  int b = blockIdx.x >> 4, sub = blockIdx.x & 15;
  for (int p = t; p < NBINS; p += 256) h[p] = 0u;
  __syncthreads();
  const float* p = data + (size_t)b*S_ + (size_t)sub*16384;
  for (int k = 0; k < 64; ++k){
    float x = p[k*256 + t];
    int bin = (int)(x*BINSCALE);
    bin = min(max(bin, 0), NBINS-1);
    atomicAdd(&h[bin], 1u);
  }
  __syncthreads();
  unsigned int* hb = hist + (size_t)(b*16 + sub)*NBINS;
  for (int q = t; q < NBINS; q += 256) hb[q] = h[q];
}

// ---- partial histograms of grad-mag computed on-the-fly from nh ----
__global__ __launch_bounds__(256) void hist_gm_kernel(const float* __restrict__ nh,
                                                      unsigned int* __restrict__ hist){
  __shared__ unsigned int h[NBINS];
  int t = threadIdx.x;
  int b = blockIdx.x >> 4, sub = blockIdx.x & 15;
  for (int p = t; p < NBINS; p += 256) h[p] = 0u;
  __syncthreads();
  const float* base = nh + (size_t)b*S_;
  int i0 = sub*16384;
  for (int k = 0; k < 64; ++k){
    int idx = i0 + k*256 + t;
    int row = idx >> 9, col = idx & 511;
    float c = base[idx];
    float dx = (col < W_-1) ? base[idx+1]   - c : 0.f;
    float dy = (row < H_-1) ? base[idx+W_]  - c : 0.f;
    float g = sqrtf(dx*dx + dy*dy + EPS_);
    int bin = (int)(g*BINSCALE);
    bin = min(max(bin, 0), NBINS-1);
    atomicAdd(&h[bin], 1u);
  }
  __syncthreads();
  unsigned int* hb = hist + (size_t)(b*16 + sub)*NBINS;
  for (int q = t; q < NBINS; q += 256) hb[q] = h[q];
}

// ---- pick order statistics ----
__global__ __launch_bounds__(256) void pick_hist_kernel(
    const unsigned int* __restrict__ hist, int r0, int r1, int r2, int r3,
    int nranks, float* __restrict__ outv, int which){
  __shared__ unsigned int part[256];
  __shared__ int s_own[4], s_rem[4];
  __shared__ float s_val[4];
  int t = threadIdx.x, b = blockIdx.x;
  const unsigned int* hb = hist + (size_t)b*16*NBINS;
  unsigned int binc[16];
  #pragma unroll
  for (int k = 0; k < 16; ++k) binc[k] = 0u;
  for (int sub = 0; sub < 16; ++sub){
    const unsigned int* hp = hb + (size_t)sub*NBINS + t*16;
    #pragma unroll
    for (int k = 0; k < 16; ++k) binc[k] += hp[k];
  }
  unsigned int sum = 0u;
  #pragma unroll
  for (int k = 0; k < 16; ++k) sum += binc[k];
  part[t] = sum;
  __syncthreads();
  if (t == 0){
    int rk[4] = {r0, r1, r2, r3};
    for (int ri = 0; ri < nranks; ++ri){
      int rem = rk[ri]; int own = 255;
      for (int q = 0; q < 256; ++q){
        if ((unsigned int)rem < part[q]){ own = q; break; }
        rem -= (int)part[q];
      }
      s_own[ri] = own; s_rem[ri] = rem;
    }
  }
  __syncthreads();
  for (int ri = 0; ri < nranks; ++ri){
    if (t == s_own[ri]){
      int rem = s_rem[ri]; int bin = t*16 + 15;
      #pragma unroll
      for (int q = 0; q < 16; ++q){
        if ((unsigned int)rem < binc[q]){ bin = t*16 + q; break; }
        rem -= (int)binc[q];
      }
      s_val[ri] = ((float)bin + 0.5f) * BINW;
    }
  }
  __syncthreads();
  if (t == 0){
    if (which == 0){
      outv[2*b+0] = s_val[0]*0.57f + s_val[1]*0.43f;   // lo (pos frac .43)
      outv[2*b+1] = s_val[2]*0.43f + s_val[3]*0.57f;   // hi (pos frac .57)
    } else {
      outv[b] = fmaxf(0.5f*(s_val[0] + s_val[1]), EPS_); // median -> sigma
    }
  }
}

// ---- N_hat only, vectorized ----
__global__ __launch_bounds__(256) void nhat_kernel(const float* __restrict__ x,
                                                   const float* __restrict__ vx2,
                                                   float* __restrict__ nh){
  size_t i4 = (size_t)blockIdx.x*256 + threadIdx.x;   // float4 index
  int b = (int)(i4 >> 16);
  float lo = vx2[2*b], hi = vx2[2*b+1];
  float inv = 1.0f/(hi - lo + EPS_);
  float4 v = ((const float4*)x)[i4];
  v.x = fminf(fmaxf((v.x-lo)*inv, 0.f), 1.f);
  v.y = fminf(fmaxf((v.y-lo)*inv, 0.f), 1.f);
  v.z = fminf(fmaxf((v.z-lo)*inv, 0.f), 1.f);
  v.w = fminf(fmaxf((v.w-lo)*inv, 0.f), 1.f);
  ((float4*)nh)[i4] = v;
}

// ---- fused primal-dual: TILE 64 / CORE 48 / 1024 thr / 1x4 px per thread ----
// Forced 2 blocks/CU x 16 waves = 32 waves/CU (arch max). State ~38 floats -> fits 64 VGPR.
#define TILE 64
#define CORE 48
#define HALO 8
#define NB 11    // ceil(512/48)
#define PSTR 68  // padded LDS row stride: 68 mod 32 = 4 -> balanced banks

#define AW_(d) (ALPHA_*(1.0f + MU_*__expf(-fabsf(d)*invs)))

__global__ __launch_bounds__(1024, 8) void pd_fused_kernel(
    const float* __restrict__ u_in,  const float* __restrict__ ub_in,
    const float* __restrict__ px_in, const float* __restrict__ py_in,
    float* __restrict__ u_out,  float* __restrict__ ub_out,
    float* __restrict__ px_out, float* __restrict__ py_out,
    const float* __restrict__ nh_g, const float* __restrict__ sig_arr,
    int T, int mode)   // mode 1 = init from nh; 2 = last launch (store clamped u)
{
  __shared__ float sA[TILE*PSTR], sB[TILE*PSTR];
  const int t = threadIdx.x;
  const int b = blockIdx.z;
  const int gi0 = blockIdx.y*CORE - HALO;
  const int gj0 = blockIdx.x*CORE - HALO;
  const float invs = 1.0f / sig_arr[b];
  const int pi = t >> 4, pj = t & 15;      // 64 rows x 16 col-groups
  const int c0 = 4*pj;                     // 1-tall x 4-wide pixels per thread
  const size_t bb = (size_t)b*S_;
  const int gi = gi0 + pi;

  // stage a full 64x64 tile (clamped-replicate halo), 4 scalar loads/thread
  #define STAGE(dst, srcP)                                         \
    _Pragma("unroll")                                              \
    for (int k = 0; k < 4; ++k){                                   \
      int p = t + k*1024; int li = p>>6, lj = p & 63;              \
      int sgi = gi0+li, sgj = gj0+lj;                              \
      int gic = min(max(sgi,0),H_-1), gjc = min(max(sgj,0),W_-1);  \
      dst[li*PSTR+lj] = srcP[bb + (size_t)gic*W_ + gjc]; }

  // nh tile -> sB (weights); ub init -> sA
  STAGE(sB, nh_g)
  if (mode == 1){ STAGE(sA, nh_g) }
  else          { STAGE(sA, ub_in) }
  __syncthreads();

  // loop-invariant LDS addresses
  const int rU = max(pi-1,0), rD = min(pi+1,TILE-1);
  const int cl = max(c0-1,0), cr = min(c0+4,TILE-1);
  const int a_o  = pi*PSTR + c0;
  const int a_up = rU*PSTR + c0;
  const int a_dn = rD*PSTR + c0;
  const int a_l  = pi*PSTR + cl;
  const int a_r  = pi*PSTR + cr;

  // ---- prologue: weights from nh (in sB) ----
  float nh_r[4], ax[4], ay[4], ayU[4], axL;
  {
    float4 n0 = *(const float4*)&sB[a_o];
    float4 nU = *(const float4*)&sB[a_up];
    float4 nD = *(const float4*)&sB[a_dn];
    float nR = sB[a_r], nL = sB[a_l];
    float n0a[4] = {n0.x,n0.y,n0.z,n0.w};
    float nUa[4] = {nU.x,nU.y,nU.z,nU.w};
    float nDa[4] = {nD.x,nD.y,nD.z,nD.w};
    const int giU = gi - 1;
    #pragma unroll
    for (int c = 0; c < 4; ++c){
      nh_r[c] = n0a[c];
      int gj = gj0 + c0 + c;
      float nhR = (c<3) ? n0a[c+1] : nR;
      bool jb = (gj < 0) || (gj >= W_-1);
      ax[c]  = jb ? 0.f : AW_(nhR - n0a[c]);
      ay[c]  = (gi  < 0 || gi  >= H_-1) ? 0.f : AW_(nDa[c] - n0a[c]);
      ayU[c] = (giU < 0 || giU >= H_-1) ? 0.f : AW_(n0a[c] - nUa[c]);
    }
    int gjL = gj0 + c0 - 1;
    float nhRL = (c0 > 0) ? n0a[0] : n0a[1];
    bool lb = (gjL < 0) || (gjL >= W_-1);
    axL = lb ? 0.f : AW_(nhRL - nL);
  }

  // ---- state: u/px/py/pxL/pyU loaded DIRECTLY from global (no halo dependency;
  // out-of-range lanes are masked by ax/ay==0 so their values never propagate) ----
  float u_r[4], px_r[4], py_r[4], pyU[4], pxL, ub_r[4], ubw[4];
  if (mode == 1){
    #pragma unroll
    for (int c = 0; c < 4; ++c){
      u_r[c] = nh_r[c]; ub_r[c] = nh_r[c];
      px_r[c] = 0.f; py_r[c] = 0.f; pyU[c] = 0.f;
    }
    pxL = 0.f;
  } else {
    int gic  = min(max(gi,0),H_-1);
    int gicU = min(max(gi-1,0),H_-1);
    int gjc4 = min(max(gj0+c0,0), W_-4);           // stays multiple of 4
    size_t go  = bb + (size_t)gic *W_ + gjc4;
    size_t goU = bb + (size_t)gicU*W_ + gjc4;
    float4 uv  = *(const float4*)&u_in[go];
    float4 pxv = *(const float4*)&px_in[go];
    float4 pyv = *(const float4*)&py_in[go];
    float4 pyu = *(const float4*)&py_in[goU];
    u_r[0]=uv.x;  u_r[1]=uv.y;  u_r[2]=uv.z;  u_r[3]=uv.w;
    px_r[0]=pxv.x; px_r[1]=pxv.y; px_r[2]=pxv.z; px_r[3]=pxv.w;
    py_r[0]=pyv.x; py_r[1]=pyv.y; py_r[2]=pyv.z; py_r[3]=pyv.w;
    pyU[0]=pyu.x; pyU[1]=pyu.y; pyU[2]=pyu.z; pyU[3]=pyu.w;
    int gjLc = min(max(gj0+c0-1,0), W_-1);
    pxL = px_in[bb + (size_t)gic*W_ + gjLc];
    float4 ubv = *(const float4*)&sA[a_o];
    ub_r[0]=ubv.x; ub_r[1]=ubv.y; ub_r[2]=ubv.z; ub_r[3]=ubv.w;
  }
  __syncthreads();

  for (int s = 0; s < T; ++s){
    float* RB = (s & 1) ? sB : sA;
    float* WB = (s & 1) ? sA : sB;
    float4 up = *(const float4*)&RB[a_up];
    float4 dn = *(const float4*)&RB[a_dn];
    float ubL = RB[a_l], ubR = RB[a_r];
    float upa[4] = {up.x,up.y,up.z,up.w};
    float dna[4] = {dn.x,dn.y,dn.z,dn.w};

    pxL = fminf(fmaxf(fmaf(SIG_, ub_r[0]-ubL, pxL), -axL), axL);
    #pragma unroll
    for (int c = 0; c < 4; ++c)
      pyU[c] = fminf(fmaxf(fmaf(SIG_, ub_r[c]-upa[c], pyU[c]), -ayU[c]), ayU[c]);
    #pragma unroll
    for (int c = 0; c < 4; ++c){
      float ubRn = (c<3) ? ub_r[c+1] : ubR;
      px_r[c] = fminf(fmaxf(fmaf(SIG_, ubRn-ub_r[c], px_r[c]), -ax[c]), ax[c]);
      py_r[c] = fminf(fmaxf(fmaf(SIG_, dna[c]-ub_r[c], py_r[c]), -ay[c]), ay[c]);
    }
    #pragma unroll
    for (int c = 0; c < 4; ++c){
      float pxl = (c>0) ? px_r[c-1] : pxL;
      float div = px_r[c] + py_r[c] - pxl - pyU[c];
      float un = fmaf(TAU_, div + nh_r[c], u_r[c]) * INV1PT_;
      ubw[c] = 2.f*un - u_r[c];
      u_r[c] = un;
    }
    *(float4*)&WB[a_o] = make_float4(ubw[0],ubw[1],ubw[2],ubw[3]);
    ub_r[0]=ubw[0]; ub_r[1]=ubw[1]; ub_r[2]=ubw[2]; ub_r[3]=ubw[3];
    __syncthreads();
  }

  // epilogue: core rows 8..55, core col-groups pj 2..13
  if (pi >= HALO && pi < HALO+CORE && pj >= 2 && pj <= 13 && gi < H_){
    int gj = gj0 + c0;
    if (gj < W_){
      size_t g = bb + (size_t)gi*W_ + gj;
      if (mode == 2){
        *(float4*)&u_out[g] = make_float4(
          fminf(fmaxf(u_r[0],0.f),1.f), fminf(fmaxf(u_r[1],0.f),1.f),
          fminf(fmaxf(u_r[2],0.f),1.f), fminf(fmaxf(u_r[3],0.f),1.f));
      } else {
        *(float4*)&u_out[g]  = make_float4(u_r[0], u_r[1], u_r[2], u_r[3]);
        *(float4*)&ub_out[g] = make_float4(ub_r[0],ub_r[1],ub_r[2],ub_r[3]);
        *(float4*)&px_out[g] = make_float4(px_r[0],px_r[1],px_r[2],px_r[3]);
        *(float4*)&py_out[g] = make_float4(py_r[0],py_r[1],py_r[2],py_r[3]);
      }
    }
  }
}

extern "C" void kernel_launch(void* const* d_in, const int* in_sizes, int n_in,
                              void* d_out, int out_size, void* d_ws, size_t ws_size,
                              hipStream_t stream){
  const float* Iy = (const float*)d_in[0];
  float* out = (float*)d_out;
  char* ws = (char*)d_ws;
  const size_t SLOT = (size_t)B_*S_*sizeof(float);
  float* slot[8];
  for (int q = 0; q < 8; ++q) slot[q] = (float*)(ws + (size_t)q*SLOT);
  float* vx2 = (float*)(ws + (size_t)8*SLOT);  // lo,hi per batch (32 floats)
  float* sig = vx2 + 32;                       // sigma per batch (16 floats)

  float* Rh  = slot[0];
  float* GBh = slot[1];
  float* Rf  = slot[5];
  float* Gf  = slot[6];
  float* xb  = slot[2];
  float* nh  = slot[3];
  unsigned int* hist_x  = (unsigned int*)(ws + (size_t)4*SLOT);   // 4 MiB
  unsigned int* hist_gm = hist_x + (size_t)256*NBINS;             // 4 MiB

  hmax_kernel<<<B_*H_, 256, 0, stream>>>(Iy, Rh, GBh);
  vscan_fwd_kernel<<<544, 256, 0, stream>>>(Rh, GBh, Rf, Gf);
  vscan_bwd_kernel<<<544, 256, 0, stream>>>(Rh, GBh, Rf, Gf, Iy, xb);
  hist_build_kernel<<<256, 256, 0, stream>>>(xb, hist_x);
  // ranks: floor/ceil of 0.01*(N-1)=2621.43 and 0.99*(N-1)=259521.57
  pick_hist_kernel<<<B_, 256, 0, stream>>>(hist_x, 2621, 2622, 259521, 259522, 4, vx2, 0);
  nhat_kernel<<<B_*S_/4/256, 256, 0, stream>>>(xb, vx2, nh);
  hist_gm_kernel<<<256, 256, 0, stream>>>(nh, hist_gm);
  // median ranks 131071, 131072
  pick_hist_kernel<<<B_, 256, 0, stream>>>(hist_gm, 131071, 131072, 0, 0, 2, sig, 1);

  float *uA = slot[1], *ubA = slot[2], *pxA = slot[5], *pyA = slot[6];
  float *uB = slot[0], *ubB = slot[4], *pxB = slot[7], *pyB = out;

  dim3 pdg(NB, NB, B_);
  pd_fused_kernel<<<pdg, 1024, 0, stream>>>(nh, nh, nh, nh,
                                            uA, ubA, pxA, pyA, nh, sig, 8, 1);
  pd_fused_kernel<<<pdg, 1024, 0, stream>>>(uA, ubA, pxA, pyA,
                                            uB, ubB, pxB, pyB, nh, sig, 8, 0);
  pd_fused_kernel<<<pdg, 1024, 0, stream>>>(uB, ubB, pxB, pyB,
                                            uA, ubA, pxA, pyA, nh, sig, 8, 0);
  // last launch: clamp u straight into out (out not read in this launch)
  pd_fused_kernel<<<pdg, 1024, 0, stream>>>(uA, ubA, pxA, pyA,
                                            out, slot[7], slot[7], slot[7], nh, sig, 6, 2);
}